// Round 23
// baseline (125.693 us; speedup 1.0000x reference)
//
#include <hip/hip_runtime.h>

// Problem constants (fixed by setup_inputs: T=8, N=2048, D=256)
#define T_ALL 8
#define T1    7
#define NPTS  2048
#define DD    256
#define NPB   32                     // 64-col blocks per frame (wave tiles)
#define NGRP  1024                   // 16-row frag groups over all frames
#define MARGIN_THR 2.0e-4f           // 2x the 9.6e-5 rigorous (C-S) margin bound
#define RC_COLS 8                    // dst cols per recheck block
#define RC_ROWS 24                   // src rows staged per recheck batch

// ws layout (floats)
#define O_ND    0                                  // fp32 normalized [16384][256]
#define O_HI    (O_ND + T_ALL*NPTS*DD)             // bf16 hi, frag layout (shorts)
#define O_LO    (O_HI + T_ALL*NPTS*DD/2)
#define O_PV1   (O_LO + T_ALL*NPTS*DD/2)           // per (row, colblock) top1
#define O_PI1   (O_PV1 + T1*NPTS*NPB)
#define O_PV2   (O_PI1 + T1*NPTS*NPB)              // per (row, colblock) top2
#define O_BEST  (O_PV2 + T1*NPTS*NPB)              // u64 [14336]
#define O_WL    (O_BEST + T1*NPTS*2)               // int per-t worklists [7][2048]
#define O_CNT   (O_WL + T1*NPTS)                   // int cntT[8]

typedef __attribute__((ext_vector_type(8))) short short8v;   // 8 bf16 (4 VGPR)
typedef __attribute__((ext_vector_type(4))) float float4v;   // MFMA acc

__device__ __forceinline__ unsigned short f2bf(float x) {    // RNE f32->bf16
    unsigned u = __float_as_uint(x);
    return (unsigned short)((u + 0x7FFFu + ((u >> 16) & 1u)) >> 16);
}
__device__ __forceinline__ float bf2f(unsigned short h) {
    return __uint_as_float(((unsigned)h) << 16);
}
// monotone pack: larger value wins; equal value -> smaller idx wins
__device__ __forceinline__ unsigned long long packVI(float v, int idx) {
    unsigned int b = __float_as_uint(v);
    b = (b & 0x80000000u) ? ~b : (b | 0x80000000u);
    return ((unsigned long long)b << 32) | (unsigned int)(NPTS - 1 - idx);
}

// ---------------------------------------------------------------------------
// Kernel 1: normalize rows; emit fp32 nd + bf16 hi/lo in MFMA-frag layout.
// Tile order [rd][group]: tile(rd, group) at shorts offset (rd*NGRP+grp)*512;
// a round's consecutive groups are CONTIGUOUS 1KB lane-contiguous tiles ->
// match loads via base pointer + immediate offsets, and global_load_lds can
// DMA them (dest = uniform base + lane*16B). A and B use the SAME (lane,e)->k
// map -> any HW k-permutation cancels in the dot product.
// ---------------------------------------------------------------------------
__global__ __launch_bounds__(256) void prep_kernel(const float* __restrict__ desc,
                                                   float* __restrict__ nd,
                                                   ushort* __restrict__ ghi,
                                                   ushort* __restrict__ glo,
                                                   int* __restrict__ cntT) {
    __shared__ ushort hiS[4096];                   // 8 KB: 8 ksteps x 512 shorts
    __shared__ ushort loS[4096];
    const int tid = threadIdx.x;
    const int grp = blockIdx.x;                    // 0..1023
    if (grp == 0 && tid < 8) cntT[tid] = 0;
    const int rl  = tid >> 4;                      // row in group
    const int kc  = tid & 15;                      // 16-float chunk
    const int row = grp * 16 + rl;

    const float* sp = desc + (size_t)row * DD + kc * 16;
    float4 v[4];
    float s = 0.f;
#pragma unroll
    for (int j = 0; j < 4; ++j) {
        v[j] = reinterpret_cast<const float4*>(sp)[j];
        s += v[j].x * v[j].x + v[j].y * v[j].y + v[j].z * v[j].z + v[j].w * v[j].w;
    }
#pragma unroll
    for (int m = 1; m <= 8; m <<= 1) s += __shfl_xor(s, m, 64);  // 16-lane row group
    float n = fmaxf(sqrtf(s), 1e-8f);

    float4 o[4];
    float* ndp = nd + (size_t)row * DD + kc * 16;
#pragma unroll
    for (int j = 0; j < 4; ++j) {
        o[j] = make_float4(v[j].x / n, v[j].y / n, v[j].z / n, v[j].w / n);
        reinterpret_cast<float4*>(ndp)[j] = o[j];
    }
    const int sbase = (kc >> 1) * 512 + rl * 8 + (kc & 1) * 4;   // shorts
#pragma unroll
    for (int g = 0; g < 4; ++g) {
        float xs[4] = {o[g].x, o[g].y, o[g].z, o[g].w};
        ushort4 h, l;
        h.x = f2bf(xs[0]); l.x = f2bf(xs[0] - bf2f(h.x));
        h.y = f2bf(xs[1]); l.y = f2bf(xs[1] - bf2f(h.y));
        h.z = f2bf(xs[2]); l.z = f2bf(xs[2] - bf2f(h.z));
        h.w = f2bf(xs[3]); l.w = f2bf(xs[3] - bf2f(h.w));
        *reinterpret_cast<ushort4*>(&hiS[sbase + g * 128]) = h;
        *reinterpret_cast<ushort4*>(&loS[sbase + g * 128]) = l;
    }
    __syncthreads();
    // copy-out: 8 tiles of 1KB per tensor, each at (rd*NGRP+grp)*1KB
    const int ch = tid >> 5;                       // rd 0..7
    const int cw = tid & 31;                       // 32 thr x 32B = 1KB
    const uint4* hs = reinterpret_cast<const uint4*>(hiS);
    const uint4* ls = reinterpret_cast<const uint4*>(loS);
    uint4* hd = reinterpret_cast<uint4*>(ghi + (((size_t)ch * NGRP + grp) << 9));
    uint4* ld = reinterpret_cast<uint4*>(glo + (((size_t)ch * NGRP + grp) << 9));
    hd[cw * 2 + 0] = hs[ch * 64 + cw * 2 + 0];
    hd[cw * 2 + 1] = hs[ch * 64 + cw * 2 + 1];
    ld[cw * 2 + 0] = ls[ch * 64 + cw * 2 + 0];
    ld[cw * 2 + 1] = ls[ch * 64 + cw * 2 + 1];
}

// ---------------------------------------------------------------------------
// Kernel 2: bf16 MFMA match, DEPTH-2 pipeline. vmcnt retires IN ISSUE ORDER,
// so the compiler's wait for al(rd) (issued after B(rd+1)'s DMA) forces
// B(rd+1) complete -- with 3 LDS buffers and B issued 2 rounds ahead, the
// round-end barrier needs NO vmcnt at all (bare s_barrier). Schedule/round:
// issueB(rd+2) -> lh(al) -> prefetch al(rd+1) -> hh(ah) -> hl(ah) ->
// prefetch ah(rd+1) -> s_barrier. Every load gets >= 1 full round (~1500cyc)
// of flight; no drain ever touches fresh ops. No role swap / no unroll
// (R21's x2-unroll spilled 26MB); live set: acc 64 + ah 16 + al 16 + b 16
// + addr ~12 <= 128 -> 4 waves/SIMD (LDS 48KB caps 3 blocks/CU).
// ---------------------------------------------------------------------------
__global__ __launch_bounds__(256, 4) void match_kernel(const ushort* __restrict__ ghi,
                                                       const ushort* __restrict__ glo,
                                                       float* __restrict__ pV1,
                                                       int* __restrict__ pI1,
                                                       float* __restrict__ pV2) {
    __shared__ __align__(16) ushort sB[3][8192];   // 48KB: 3 bufs x (8 hi + 8 lo) KB
    const int bid = blockIdx.x;                    // 1792 = 7 * 16 * 16
    const int swz = (bid & 7) * (1792 / 8) + (bid >> 3);   // bijective
    const int t   = swz >> 8;
    const int rbB = (swz >> 4) & 15;               // 128-row block panel
    const int cbB = swz & 15;                      // 128-col block panel
    const int tid = threadIdx.x;
    const int w   = tid >> 6;
    const int l   = tid & 63;
    const int wr  = w >> 1;                        // wave row half
    const int wc  = w & 1;                         // wave col half
    const int rb  = rbB * 2 + wr;                  // 64-row wave panel (0..31)
    const int cb  = cbB * 2 + wc;                  // 64-col wave panel (0..31)
    const size_t l8 = (size_t)(l << 3);            // lane's 8 shorts

    const int agrp  = t * 128 + rb * 4;            // A frag groups (16 rows each)
    const int bgrpB = (t + 1) * 128 + cbB * 8;     // block's 8 B groups
    const size_t RSTRIDE = (size_t)NGRP << 9;      // shorts per rd step

    // A: direct-load running pointers
    const ushort* pAh = ghi + ((size_t)agrp << 9) + l8;
    const ushort* pAl = glo + ((size_t)agrp << 9) + l8;
    // B DMA: wave w owns tiles 4w..4w+3; tensor = w>>1, groups (w&1)*4 + f
    const ushort* pD  = ((w >> 1) ? glo : ghi)
                      + ((size_t)(bgrpB + (w & 1) * 4) << 9) + l8;
    const int tile0 = w * 4;                       // LDS tile index base

    auto issueB = [&](const ushort* src, int buf) {
#pragma unroll
        for (int f = 0; f < 4; ++f)
            __builtin_amdgcn_global_load_lds(
                (const __attribute__((address_space(1))) unsigned int*)(src + (f << 9)),
                (__attribute__((address_space(3))) unsigned int*)&sB[buf][(tile0 + f) << 9],
                16, 0, 0);
    };

    float4v acc[4][4];
#pragma unroll
    for (int fa = 0; fa < 4; ++fa)
#pragma unroll
        for (int fb = 0; fb < 4; ++fb) acc[fa][fb] = (float4v){0.f, 0.f, 0.f, 0.f};

    short8v ah[4], al[4], b[4];                    // b time-shares bh then bl

    auto mma = [&](const short8v* a) {
#pragma unroll
        for (int fa = 0; fa < 4; ++fa)
#pragma unroll
            for (int fb = 0; fb < 4; ++fb)
                acc[fa][fb] = __builtin_amdgcn_mfma_f32_16x16x32_bf16(a[fa], b[fb], acc[fa][fb], 0, 0, 0);
    };

    // prologue: B(0)->buf0, B(1)->buf1, al(0), ah(0)
    issueB(pD, 0); pD += RSTRIDE;
    issueB(pD, 1); pD += RSTRIDE;
#pragma unroll
    for (int f = 0; f < 4; ++f)
        al[f] = *reinterpret_cast<const short8v*>(pAl + (f << 9));
    pAl += RSTRIDE;
#pragma unroll
    for (int f = 0; f < 4; ++f)
        ah[f] = *reinterpret_cast<const short8v*>(pAh + (f << 9));
    pAh += RSTRIDE;
    asm volatile("s_waitcnt vmcnt(12)" ::: "memory");   // B(0) landed
    __builtin_amdgcn_s_barrier();

    int cur = 0, nx2 = 2;                          // rd's buffer; rd+2's buffer
#pragma unroll 1
    for (int rd = 0; rd < 8; ++rd) {
        if (rd < 6) { issueB(pD, nx2); pD += RSTRIDE; }   // B two rounds ahead
        const ushort* Sb = sB[cur];
        // bh frags from LDS
#pragma unroll
        for (int f = 0; f < 4; ++f)
            b[f]  = *reinterpret_cast<const short8v*>(&Sb[((wc * 4 + f) << 9) + (l << 3)]);
        mma(al);                                   // pass lh: al x bh (prefetched)
        if (rd < 7) {
#pragma unroll
            for (int f = 0; f < 4; ++f)            // al(rd+1); al dead after lh
                al[f] = *reinterpret_cast<const short8v*>(pAl + (f << 9));
            pAl += RSTRIDE;
        }
        mma(ah);                                   // pass hh: ah x bh (prefetched)
        // bl frags from LDS: reuse b
#pragma unroll
        for (int f = 0; f < 4; ++f)
            b[f]  = *reinterpret_cast<const short8v*>(&Sb[((8 + wc * 4 + f) << 9) + (l << 3)]);
        mma(ah);                                   // pass hl: ah x bl
        if (rd < 7) {
#pragma unroll
            for (int f = 0; f < 4; ++f)            // ah(rd+1); ah dead after hl
                ah[f] = *reinterpret_cast<const short8v*>(pAh + (f << 9));
            pAh += RSTRIDE;
            // B(rd+1) already retired (in-order vmcnt, forced by al(rd) wait)
            asm volatile("s_barrier" ::: "memory");
        }
        cur = (cur == 2) ? 0 : cur + 1;
        nx2 = (nx2 == 2) ? 0 : nx2 + 1;
    }

    // ---- epilogue (in-wave): D row = fa*16+4*(l>>4)+r, col = cb*64+fb*16+(l&15)
#pragma unroll
    for (int fa = 0; fa < 4; ++fa) {
#pragma unroll
        for (int r = 0; r < 4; ++r) {
            float v1 = -3.0e38f, v2 = -3.0e38f; int i1 = 0;
#pragma unroll
            for (int fb = 0; fb < 4; ++fb) {
                float x  = acc[fa][fb][r];
                int  col = cb * 64 + fb * 16 + (l & 15);
                if (x > v1) { v2 = v1; v1 = x; i1 = col; }
                else        { v2 = fmaxf(v2, x); }
            }
#pragma unroll
            for (int m = 1; m <= 8; m <<= 1) {     // 16-lane butterfly
                float ov1 = __shfl_xor(v1, m);
                int   oi1 = __shfl_xor(i1, m);
                float ov2 = __shfl_xor(v2, m);
                bool take = (ov1 > v1) || (ov1 == v1 && oi1 < i1);
                float nv2 = take ? fmaxf(ov2, v1) : fmaxf(v2, ov1);
                v1 = take ? ov1 : v1;  i1 = take ? oi1 : i1;  v2 = nv2;
            }
            if ((l & 15) == 0) {
                int grow = t * NPTS + rb * 64 + fa * 16 + (l >> 4) * 4 + r;
                int idx  = grow * NPB + cb;
                pV1[idx] = v1; pI1[idx] = i1; pV2[idx] = v2;
            }
        }
    }
}

// ---------------------------------------------------------------------------
// Kernel 3: global top-2 margin per row; near-ties -> per-t worklist; safe
// rows commit approx best (value error <= 4.8e-5 << bf16-granular bar).
// ---------------------------------------------------------------------------
__global__ __launch_bounds__(256) void margin_kernel(const float* __restrict__ pV1,
                                                     const int* __restrict__ pI1,
                                                     const float* __restrict__ pV2,
                                                     unsigned long long* __restrict__ best,
                                                     int* __restrict__ wlT,
                                                     int* __restrict__ cntT) {
    int r = blockIdx.x * 256 + threadIdx.x;        // 0..14335
    int t = r >> 11;
    float v1 = -3.0e38f, v2 = -3.0e38f; int i1 = 0;
#pragma unroll
    for (int cbk = 0; cbk < NPB; ++cbk) {          // ascending -> first-occurrence
        int idx = r * NPB + cbk;
        float a1 = pV1[idx]; int ai = pI1[idx]; float a2 = pV2[idx];
        if (a1 > v1) { v2 = fmaxf(v1, a2); v1 = a1; i1 = ai; }
        else         { v2 = fmaxf(v2, a1); }
    }
    if (v1 - v2 < MARGIN_THR) {
        best[r] = 0ull;
        int slot = atomicAdd(&cntT[t], 1);
        wlT[t * NPTS + slot] = r & (NPTS - 1);     // row within frame
    } else {
        best[r] = packVI(v1, i1);
    }
}

// ---------------------------------------------------------------------------
// Kernel 4: exact fp32 rescore, loop-inverted + wave-parallel rows.
// Block = (t, 8-col slab); batch-stage <=24 flagged src rows + the dst slab
// in conflict-free [*][8][33] layouts; wave w handles rows w, w+4, ...
// independently; one atomicMax per row per slab (order-independent).
// ---------------------------------------------------------------------------
__global__ __launch_bounds__(256) void recheck_kernel(const float* __restrict__ nd,
                                                      const int* __restrict__ wlT,
                                                      const int* __restrict__ cntT,
                                                      unsigned long long* __restrict__ best) {
    __shared__ float dstS[RC_COLS][8][33];         // 8.25 KB  [col][kseg][k]
    __shared__ float srcS[RC_ROWS][8][33];         // 24.75 KB [row][kseg][k]
    const int t   = blockIdx.x >> 8;               // grid = 7 * 256
    const int cc  = blockIdx.x & 255;
    const int nr  = cntT[t];
    if (nr == 0) return;
    const int tid  = threadIdx.x;
    const int w    = tid >> 6;
    const int l    = tid & 63;
    const int col0 = cc * RC_COLS;

    {   // stage 8 dst cols: thread col=tid>>5, 2 float4 (8 floats) each
        const int col = tid >> 5;
        const int k8  = tid & 31;
        const float* dp = nd + ((size_t)((t + 1) * NPTS) + col0 + col) * DD;
#pragma unroll
        for (int j = 0; j < 2; ++j) {
            float4 v = reinterpret_cast<const float4*>(dp)[k8 * 2 + j];
            int k = (k8 * 2 + j) * 4;
            dstS[col][k >> 5][k & 31]       = v.x;
            dstS[col][(k+1) >> 5][(k+1)&31] = v.y;
            dstS[col][(k+2) >> 5][(k+2)&31] = v.z;
            dstS[col][(k+3) >> 5][(k+3)&31] = v.w;
        }
    }

#pragma unroll 1
    for (int base = 0; base < nr; base += RC_ROWS) {
        const int nb = min(RC_ROWS, nr - base);
        __syncthreads();                           // srcS free (dstS ready, 1st)
        for (int idx = tid; idx < nb * 64; idx += 256) {
            const int ri = idx >> 6, ln = idx & 63;
            const int row = wlT[t * NPTS + base + ri];
            float4 v = reinterpret_cast<const float4*>(
                nd + ((size_t)(t * NPTS) + row) * DD)[ln];
            int k = ln * 4;
            srcS[ri][k >> 5][k & 31]       = v.x;
            srcS[ri][(k+1) >> 5][(k+1)&31] = v.y;
            srcS[ri][(k+2) >> 5][(k+2)&31] = v.z;
            srcS[ri][(k+3) >> 5][(k+3)&31] = v.w;
        }
        __syncthreads();                           // batch staged

        const int colx = l & 7, ks = l >> 3;
#pragma unroll 1
        for (int ri = w; ri < nb; ri += 4) {       // waves independent
            const int row = wlT[t * NPTS + base + ri];
            const int r   = t * NPTS + row;
            float p = 0.f;
#pragma unroll
            for (int k = 0; k < 32; ++k)
                p = fmaf(srcS[ri][ks][k], dstS[colx][ks][k], p);
            p += __shfl_xor(p, 8); p += __shfl_xor(p, 16); p += __shfl_xor(p, 32);
            float bv = p; int bi = col0 + colx;
#pragma unroll
            for (int m = 1; m <= 4; m <<= 1) {     // top-1 across 8 cols
                float ov = __shfl_xor(bv, m);
                int   oi = __shfl_xor(bi, m);
                if (ov > bv || (ov == bv && oi < bi)) { bv = ov; bi = oi; }
            }
            if (l == 0) atomicMax(&best[r], packVI(bv, bi));
        }
    }
}

// ---------------------------------------------------------------------------
// Kernel 5: unpack best[], gather matched points, write outputs.
// ---------------------------------------------------------------------------
__global__ __launch_bounds__(256) void final_kernel(const unsigned long long* __restrict__ best,
                                                    const float* __restrict__ pts,
                                                    float* __restrict__ out) {
    int r = blockIdx.x * 256 + threadIdx.x;
    int t = r >> 11;
    unsigned long long p = best[r];
    int idx = NPTS - 1 - (int)(p & 0xFFFFFFFFull);
    unsigned int b = (unsigned int)(p >> 32);
    b = (b & 0x80000000u) ? (b & 0x7FFFFFFFu) : ~b;
    out[(size_t)T1 * NPTS * 2 + r] = __uint_as_float(b);
    const float* q = pts + ((size_t)((t + 1) * NPTS) + idx) * 2;
    out[(size_t)r * 2 + 0] = q[0];
    out[(size_t)r * 2 + 1] = q[1];
}

// ---------------------------------------------------------------------------
extern "C" void kernel_launch(void* const* d_in, const int* in_sizes, int n_in,
                              void* d_out, int out_size, void* d_ws, size_t ws_size,
                              hipStream_t stream) {
    const float* desc = (const float*)d_in[0];     // [8, 2048, 256] fp32
    const float* pts  = (const float*)d_in[1];     // [8, 2048, 2]   fp32
    float* ws = (float*)d_ws;
    float* nd  = ws + O_ND;
    ushort* ghi = (ushort*)(ws + O_HI);
    ushort* glo = (ushort*)(ws + O_LO);
    float* pV1 = ws + O_PV1;
    int*   pI1 = (int*)(ws + O_PI1);
    float* pV2 = ws + O_PV2;
    unsigned long long* best = (unsigned long long*)(ws + O_BEST);
    int* wlT  = (int*)(ws + O_WL);
    int* cntT = (int*)(ws + O_CNT);

    prep_kernel<<<T_ALL * NPTS / 16, 256, 0, stream>>>(desc, nd, ghi, glo, cntT);
    match_kernel<<<T1 * 16 * 16, 256, 0, stream>>>(ghi, glo, pV1, pI1, pV2);
    margin_kernel<<<(T1 * NPTS) / 256, 256, 0, stream>>>(pV1, pI1, pV2, best, wlT, cntT);
    recheck_kernel<<<T1 * 256, 256, 0, stream>>>(nd, wlT, cntT, best);
    final_kernel<<<(T1 * NPTS) / 256, 256, 0, stream>>>(best, pts, (float*)d_out);
}

// Round 24
// 96.988 us; speedup vs baseline: 1.2960x; 1.2960x over previous
//
#include <hip/hip_runtime.h>

// Problem constants (fixed by setup_inputs: T=8, N=2048, D=256)
#define T_ALL 8
#define T1    7
#define NPTS  2048
#define DD    256
#define NPB   32                     // 64-col blocks per frame (wave tiles)
#define NGRP  1024                   // 16-row frag groups over all frames
#define MARGIN_THR 2.0e-4f           // > 2x the 9.6e-5 rigorous (C-S) margin bound

// ws layout (floats)
#define O_ND    0                                  // fp32 normalized [16384][256]
#define O_HI    (O_ND + T_ALL*NPTS*DD)             // bf16 hi, frag layout (shorts)
#define O_LO    (O_HI + T_ALL*NPTS*DD/2)
#define O_PV1   (O_LO + T_ALL*NPTS*DD/2)           // per (row, colblock) top1
#define O_PI1   (O_PV1 + T1*NPTS*NPB)
#define O_PV2   (O_PI1 + T1*NPTS*NPB)              // per (row, colblock) top2
#define O_WL64  (O_PV2 + T1*NPTS*NPB)              // u64 worklist {mask,row} [T1*NPTS]
#define O_CNT   (O_WL64 + T1*NPTS*2)               // int cntT[8]

typedef __attribute__((ext_vector_type(8))) short short8v;   // 8 bf16 (4 VGPR)
typedef __attribute__((ext_vector_type(4))) float float4v;   // MFMA acc

__device__ __forceinline__ unsigned short f2bf(float x) {    // RNE f32->bf16
    unsigned u = __float_as_uint(x);
    return (unsigned short)((u + 0x7FFFu + ((u >> 16) & 1u)) >> 16);
}
__device__ __forceinline__ float bf2f(unsigned short h) {
    return __uint_as_float(((unsigned)h) << 16);
}

// ---------------------------------------------------------------------------
// Kernel 1: normalize rows; emit fp32 nd + bf16 hi/lo in MFMA-frag layout.
// Tile order [rd][group]: tile(rd, group) at shorts offset (rd*NGRP+grp)*512;
// a round's consecutive groups are CONTIGUOUS 1KB lane-contiguous tiles ->
// match loads via base pointer + immediate offsets, and global_load_lds can
// DMA them. A and B use the SAME (lane,e)->k map -> HW k-permutation cancels.
// ---------------------------------------------------------------------------
__global__ __launch_bounds__(256) void prep_kernel(const float* __restrict__ desc,
                                                   float* __restrict__ nd,
                                                   ushort* __restrict__ ghi,
                                                   ushort* __restrict__ glo,
                                                   int* __restrict__ cntT) {
    __shared__ ushort hiS[4096];                   // 8 KB: 8 ksteps x 512 shorts
    __shared__ ushort loS[4096];
    const int tid = threadIdx.x;
    const int grp = blockIdx.x;                    // 0..1023
    if (grp == 0 && tid < 8) cntT[tid] = 0;
    const int rl  = tid >> 4;                      // row in group
    const int kc  = tid & 15;                      // 16-float chunk
    const int row = grp * 16 + rl;

    const float* sp = desc + (size_t)row * DD + kc * 16;
    float4 v[4];
    float s = 0.f;
#pragma unroll
    for (int j = 0; j < 4; ++j) {
        v[j] = reinterpret_cast<const float4*>(sp)[j];
        s += v[j].x * v[j].x + v[j].y * v[j].y + v[j].z * v[j].z + v[j].w * v[j].w;
    }
#pragma unroll
    for (int m = 1; m <= 8; m <<= 1) s += __shfl_xor(s, m, 64);  // 16-lane row group
    float n = fmaxf(sqrtf(s), 1e-8f);

    float4 o[4];
    float* ndp = nd + (size_t)row * DD + kc * 16;
#pragma unroll
    for (int j = 0; j < 4; ++j) {
        o[j] = make_float4(v[j].x / n, v[j].y / n, v[j].z / n, v[j].w / n);
        reinterpret_cast<float4*>(ndp)[j] = o[j];
    }
    const int sbase = (kc >> 1) * 512 + rl * 8 + (kc & 1) * 4;   // shorts
#pragma unroll
    for (int g = 0; g < 4; ++g) {
        float xs[4] = {o[g].x, o[g].y, o[g].z, o[g].w};
        ushort4 h, l;
        h.x = f2bf(xs[0]); l.x = f2bf(xs[0] - bf2f(h.x));
        h.y = f2bf(xs[1]); l.y = f2bf(xs[1] - bf2f(h.y));
        h.z = f2bf(xs[2]); l.z = f2bf(xs[2] - bf2f(h.z));
        h.w = f2bf(xs[3]); l.w = f2bf(xs[3] - bf2f(h.w));
        *reinterpret_cast<ushort4*>(&hiS[sbase + g * 128]) = h;
        *reinterpret_cast<ushort4*>(&loS[sbase + g * 128]) = l;
    }
    __syncthreads();
    // copy-out: 8 tiles of 1KB per tensor, each at (rd*NGRP+grp)*1KB
    const int ch = tid >> 5;                       // rd 0..7
    const int cw = tid & 31;                       // 32 thr x 32B = 1KB
    const uint4* hs = reinterpret_cast<const uint4*>(hiS);
    const uint4* ls = reinterpret_cast<const uint4*>(loS);
    uint4* hd = reinterpret_cast<uint4*>(ghi + (((size_t)ch * NGRP + grp) << 9));
    uint4* ld = reinterpret_cast<uint4*>(glo + (((size_t)ch * NGRP + grp) << 9));
    hd[cw * 2 + 0] = hs[ch * 64 + cw * 2 + 0];
    hd[cw * 2 + 1] = hs[ch * 64 + cw * 2 + 1];
    ld[cw * 2 + 0] = ls[ch * 64 + cw * 2 + 0];
    ld[cw * 2 + 1] = ls[ch * 64 + cw * 2 + 1];
}

// ---------------------------------------------------------------------------
// Kernel 2 (VERBATIM R22 -- best measured config, 56.4us): bf16 MFMA match,
// hybrid staging (B via global_load_lds dbuf, A direct) + half-prefetch of
// al. Pass order lh -> hh -> hl; round-end s_waitcnt vmcnt(4) drains only
// the B DMA (al prefetch flies through). 124 regs -> 4 waves/SIMD.
// R23's depth-2 (3 bufs) cost VGPR 88/occ 19% -> 73us: REVERTED.
// ---------------------------------------------------------------------------
__global__ __launch_bounds__(256, 4) void match_kernel(const ushort* __restrict__ ghi,
                                                       const ushort* __restrict__ glo,
                                                       float* __restrict__ pV1,
                                                       int* __restrict__ pI1,
                                                       float* __restrict__ pV2) {
    __shared__ __align__(16) ushort sB[2][8192];   // 32KB: 2 bufs x (8 hi + 8 lo) KB
    const int bid = blockIdx.x;                    // 1792 = 7 * 16 * 16
    const int swz = (bid & 7) * (1792 / 8) + (bid >> 3);   // bijective
    const int t   = swz >> 8;
    const int rbB = (swz >> 4) & 15;               // 128-row block panel
    const int cbB = swz & 15;                      // 128-col block panel
    const int tid = threadIdx.x;
    const int w   = tid >> 6;
    const int l   = tid & 63;
    const int wr  = w >> 1;                        // wave row half
    const int wc  = w & 1;                         // wave col half
    const int rb  = rbB * 2 + wr;                  // 64-row wave panel (0..31)
    const int cb  = cbB * 2 + wc;                  // 64-col wave panel (0..31)
    const size_t l8 = (size_t)(l << 3);            // lane's 8 shorts

    const int agrp  = t * 128 + rb * 4;            // A frag groups (16 rows each)
    const int bgrpB = (t + 1) * 128 + cbB * 8;     // block's 8 B groups
    const size_t RSTRIDE = (size_t)NGRP << 9;      // shorts per rd step

    const ushort* pAh = ghi + ((size_t)agrp << 9) + l8;
    const ushort* pAl = glo + ((size_t)agrp << 9) + l8;
    const ushort* pD  = ((w >> 1) ? glo : ghi)
                      + ((size_t)(bgrpB + (w & 1) * 4) << 9) + l8;
    const int tile0 = w * 4;                       // LDS tile index base

    auto issueB = [&](const ushort* src, int buf) {
#pragma unroll
        for (int f = 0; f < 4; ++f)
            __builtin_amdgcn_global_load_lds(
                (const __attribute__((address_space(1))) unsigned int*)(src + (f << 9)),
                (__attribute__((address_space(3))) unsigned int*)&sB[buf][(tile0 + f) << 9],
                16, 0, 0);
    };

    float4v acc[4][4];
#pragma unroll
    for (int fa = 0; fa < 4; ++fa)
#pragma unroll
        for (int fb = 0; fb < 4; ++fb) acc[fa][fb] = (float4v){0.f, 0.f, 0.f, 0.f};

    short8v ah[4], al[4], b[4];                    // b time-shares bh then bl

    auto mma = [&](const short8v* a) {
#pragma unroll
        for (int fa = 0; fa < 4; ++fa)
#pragma unroll
            for (int fb = 0; fb < 4; ++fb)
                acc[fa][fb] = __builtin_amdgcn_mfma_f32_16x16x32_bf16(a[fa], b[fb], acc[fa][fb], 0, 0, 0);
    };

    issueB(pD, 0); pD += RSTRIDE;                  // round 0 B -> buf0
#pragma unroll
    for (int f = 0; f < 4; ++f)                    // round 0 al (prefetched)
        al[f] = *reinterpret_cast<const short8v*>(pAl + (f << 9));
    pAl += RSTRIDE;
    __syncthreads();                               // buf0 ready

#pragma unroll 1
    for (int rd = 0; rd < 8; ++rd) {
        const int cur = rd & 1;
        if (rd < 7) { issueB(pD, cur ^ 1); pD += RSTRIDE; }   // next B under compute
        const ushort* Sb = sB[cur];
#pragma unroll
        for (int f = 0; f < 4; ++f)
            b[f]  = *reinterpret_cast<const short8v*>(&Sb[((wc * 4 + f) << 9) + (l << 3)]);
#pragma unroll
        for (int f = 0; f < 4; ++f)                // this round's ah (covered by lh)
            ah[f] = *reinterpret_cast<const short8v*>(pAh + (f << 9));
        mma(al);                                   // pass lh: al x bh (prefetched)
        if (rd < 7) {
#pragma unroll
            for (int f = 0; f < 4; ++f)            // al for rd+1 (al dead after lh)
                al[f] = *reinterpret_cast<const short8v*>(pAl + (f << 9));
            pAl += RSTRIDE;
        }
        mma(ah);                                   // pass hh: ah x bh
#pragma unroll
        for (int f = 0; f < 4; ++f)
            b[f]  = *reinterpret_cast<const short8v*>(&Sb[((8 + wc * 4 + f) << 9) + (l << 3)]);
        mma(ah);                                   // pass hl: ah x bl
        pAh += RSTRIDE;
        if (rd < 7) {
            asm volatile("s_waitcnt vmcnt(4)" ::: "memory");
            __builtin_amdgcn_s_barrier();
        }
    }

    // ---- epilogue (in-wave): D row = fa*16+4*(l>>4)+r, col = cb*64+fb*16+(l&15)
#pragma unroll
    for (int fa = 0; fa < 4; ++fa) {
#pragma unroll
        for (int r = 0; r < 4; ++r) {
            float v1 = -3.0e38f, v2 = -3.0e38f; int i1 = 0;
#pragma unroll
            for (int fb = 0; fb < 4; ++fb) {
                float x  = acc[fa][fb][r];
                int  col = cb * 64 + fb * 16 + (l & 15);
                if (x > v1) { v2 = v1; v1 = x; i1 = col; }
                else        { v2 = fmaxf(v2, x); }
            }
#pragma unroll
            for (int m = 1; m <= 8; m <<= 1) {     // 16-lane butterfly
                float ov1 = __shfl_xor(v1, m);
                int   oi1 = __shfl_xor(i1, m);
                float ov2 = __shfl_xor(v2, m);
                bool take = (ov1 > v1) || (ov1 == v1 && oi1 < i1);
                float nv2 = take ? fmaxf(ov2, v1) : fmaxf(v2, ov1);
                v1 = take ? ov1 : v1;  i1 = take ? oi1 : i1;  v2 = nv2;
            }
            if ((l & 15) == 0) {
                int grow = t * NPTS + rb * 64 + fa * 16 + (l >> 4) * 4 + r;
                int idx  = grow * NPB + cb;
                pV1[idx] = v1; pI1[idx] = i1; pV2[idx] = v2;
            }
        }
    }
}

// ---------------------------------------------------------------------------
// Kernel 3: margin + DIRECT OUTPUT for safe rows. Flagged rows get a
// worklist entry {candidate mask, row}: colblock cbk can contain the true
// argmax only if pV1[cbk] >= v1 - THR (true(c*) >= v1-e and approx >= true-e
// with e=4.8e-5 < THR/2). Safe rows: approx argmax == true argmax (margin
// >= THR > 2e) and approx confidence error <= e << bf16 ulp -> write out.
// ---------------------------------------------------------------------------
__global__ __launch_bounds__(256) void margin_kernel(const float* __restrict__ pV1,
                                                     const int* __restrict__ pI1,
                                                     const float* __restrict__ pV2,
                                                     const float* __restrict__ pts,
                                                     float* __restrict__ out,
                                                     unsigned long long* __restrict__ wl64,
                                                     int* __restrict__ cntT) {
    int r = blockIdx.x * 256 + threadIdx.x;        // 0..14335
    int t = r >> 11;
    float v1 = -3.0e38f, v2 = -3.0e38f; int i1 = 0;
#pragma unroll
    for (int cbk = 0; cbk < NPB; ++cbk) {          // ascending -> first-occurrence
        int idx = r * NPB + cbk;
        float a1 = pV1[idx]; int ai = pI1[idx]; float a2 = pV2[idx];
        if (a1 > v1) { v2 = fmaxf(v1, a2); v1 = a1; i1 = ai; }
        else         { v2 = fmaxf(v2, a1); }
    }
    if (v1 - v2 < MARGIN_THR) {
        unsigned int mask = 0;
#pragma unroll
        for (int cbk = 0; cbk < NPB; ++cbk)
            if (pV1[r * NPB + cbk] >= v1 - MARGIN_THR) mask |= (1u << cbk);
        int slot = atomicAdd(&cntT[t], 1);
        wl64[t * NPTS + slot] = ((unsigned long long)mask << 32) | (unsigned)(r & (NPTS - 1));
    } else {
        out[(size_t)T1 * NPTS * 2 + r] = v1;
        const float* q = pts + ((size_t)((t + 1) * NPTS) + i1) * 2;
        out[(size_t)r * 2 + 0] = q[0];
        out[(size_t)r * 2 + 1] = q[1];
    }
}

// ---------------------------------------------------------------------------
// Kernel 4: candidate-filtered exact rescore. ONE block per flagged row
// (grid-strided): stage the src row (1KB LDS); wave wv handles every 4th
// candidate colblock (64 cols = 64 lanes); exact ascending-k fmaf dot per
// col; top-1 with min-idx tie-break across lanes then waves; block writes
// the output directly (no atomics, no final kernel).
// ---------------------------------------------------------------------------
__global__ __launch_bounds__(256) void recheck_kernel(const float* __restrict__ nd,
                                                      const unsigned long long* __restrict__ wl64,
                                                      const int* __restrict__ cntT,
                                                      const float* __restrict__ pts,
                                                      float* __restrict__ out) {
    __shared__ float sSrc[DD];
    __shared__ float rV[4];
    __shared__ int   rI[4];
    const int t   = blockIdx.x >> 6;               // grid = 7 * 64
    const int i0  = blockIdx.x & 63;
    const int cnt = cntT[t];
    const int tid = threadIdx.x;
    const int w   = tid >> 6;
    const int l   = tid & 63;

#pragma unroll 1
    for (int i = i0; i < cnt; i += 64) {
        const unsigned long long e = wl64[t * NPTS + i];
        const int row = (int)(e & (NPTS - 1));
        const unsigned int mask = (unsigned int)(e >> 32);
        __syncthreads();                           // sSrc/rV reuse
        if (tid < 64)
            reinterpret_cast<float4*>(sSrc)[tid] =
                reinterpret_cast<const float4*>(nd + ((size_t)(t * NPTS) + row) * DD)[tid];
        __syncthreads();

        float bv = -3.0e38f; int bi = 0;
        int j = 0;
#pragma unroll 1
        for (int cbk = 0; cbk < NPB; ++cbk) {
            if (!((mask >> cbk) & 1u)) continue;
            if ((j & 3) == w) {                    // this wave's item
                const int col = cbk * 64 + l;
                const float* dp = nd + ((size_t)((t + 1) * NPTS) + col) * DD;
                float a = 0.f;
#pragma unroll
                for (int k4 = 0; k4 < 64; ++k4) {  // sequential ascending k
                    float4 s4 = reinterpret_cast<const float4*>(sSrc)[k4];
                    float4 d4 = reinterpret_cast<const float4*>(dp)[k4];
                    a = fmaf(s4.x, d4.x, a); a = fmaf(s4.y, d4.y, a);
                    a = fmaf(s4.z, d4.z, a); a = fmaf(s4.w, d4.w, a);
                }
                if (a > bv || (a == bv && col < bi)) { bv = a; bi = col; }
            }
            ++j;
        }
#pragma unroll
        for (int m = 1; m <= 32; m <<= 1) {        // 64-lane butterfly top-1
            float ov = __shfl_xor(bv, m);
            int   oi = __shfl_xor(bi, m);
            if (ov > bv || (ov == bv && oi < bi)) { bv = ov; bi = oi; }
        }
        if (l == 0) { rV[w] = bv; rI[w] = bi; }
        __syncthreads();
        if (tid == 0) {
            float fv = rV[0]; int fi = rI[0];
#pragma unroll
            for (int q = 1; q < 4; ++q) {
                if (rV[q] > fv || (rV[q] == fv && rI[q] < fi)) { fv = rV[q]; fi = rI[q]; }
            }
            const int r = t * NPTS + row;
            out[(size_t)T1 * NPTS * 2 + r] = fv;
            const float* qp = pts + ((size_t)((t + 1) * NPTS) + fi) * 2;
            out[(size_t)r * 2 + 0] = qp[0];
            out[(size_t)r * 2 + 1] = qp[1];
        }
    }
}

// ---------------------------------------------------------------------------
extern "C" void kernel_launch(void* const* d_in, const int* in_sizes, int n_in,
                              void* d_out, int out_size, void* d_ws, size_t ws_size,
                              hipStream_t stream) {
    const float* desc = (const float*)d_in[0];     // [8, 2048, 256] fp32
    const float* pts  = (const float*)d_in[1];     // [8, 2048, 2]   fp32
    float* ws = (float*)d_ws;
    float* nd  = ws + O_ND;
    ushort* ghi = (ushort*)(ws + O_HI);
    ushort* glo = (ushort*)(ws + O_LO);
    float* pV1 = ws + O_PV1;
    int*   pI1 = (int*)(ws + O_PI1);
    float* pV2 = ws + O_PV2;
    unsigned long long* wl64 = (unsigned long long*)(ws + O_WL64);
    int* cntT = (int*)(ws + O_CNT);
    float* out = (float*)d_out;

    prep_kernel<<<T_ALL * NPTS / 16, 256, 0, stream>>>(desc, nd, ghi, glo, cntT);
    match_kernel<<<T1 * 16 * 16, 256, 0, stream>>>(ghi, glo, pV1, pI1, pV2);
    margin_kernel<<<(T1 * NPTS) / 256, 256, 0, stream>>>(pV1, pI1, pV2, pts, out, wl64, cntT);
    recheck_kernel<<<T1 * 64, 256, 0, stream>>>(nd, wl64, cntT, pts, out);
}